// Round 5
// baseline (979.731 us; speedup 1.0000x reference)
//
#include <hip/hip_runtime.h>
#include <cmath>

#define NN 4096
#define SEQ 41
#define VEC 15
#define TT 8
#define EMBD 32
#define LDIM 256
#define RED 64

// ---- workspace layout (bytes) ----
#define WS_H       0                      // h: N*32 f32  (ALIASED by chunks after k_emb)
#define WS_CHUNKS  0                      // chunks: 32*N f32 (written by k_dtile, after h dead)
#define WS_EMB     524288                 // emb: N*32 f32
#define WS_SQN     1048576                // sqnorm: N f32
#define WS_ROWSUM  1064960                // rowsum: N f32
#define WS_ROWMIN  1081344                // rowmin: N f32
#define WS_ROWMAX  1097728                // rowmax: N f32
#define WS_POSV    1114112                // pos_vec: N*64 f32
#define WS_NEGV    2162688                // neg_vec: N*64 f32
#define WS_STATS   3211264                // mu[32], istd[32] f32
#define WS_SIMS    3211520                // 2 doubles: pos_sim, neg_sim
#define WS_PAR     3211536                // 4 f32: avg, mnt, rng

// output layout: final_feature [N*64], loss [1], D [N*N]
#define OUT_LOSS  (NN*RED)
#define OUT_D     (NN*RED + 1)

// f32 numpy-mimic: interpolation + h = tanh(flat@W1 + b1)
__global__ __launch_bounds__(64) void k_interp_h(
    const float* __restrict__ A, const int* __restrict__ C,
    const float* __restrict__ W1, const float* __restrict__ b1,
    float* __restrict__ h)
{
  __shared__ float flat[TT*VEC];
  const int n = blockIdx.x;
  const int t = threadIdx.x;
  const int st = C[2*n], en = C[2*n+1];
  const int len = en - st + 1;
  const float scale = __fdiv_rn((float)len, 8.0f);   // exact
  const float* Arow = A + ((size_t)n*SEQ + st) * VEC;
  for (int idx = t; idx < TT*VEC; idx += 64) {
    int j = idx / VEC, k = idx - j*VEC;
    float jf = (float)j + 0.5f;                               // exact
    float src = fmaxf(__fsub_rn(__fmul_rn(scale, jf), 0.5f), 0.0f);
    int i0 = min((int)floorf(src), len-1);
    int i1 = min(i0+1, len-1);
    float w = __fsub_rn(src, (float)i0);
    float g0 = Arow[i0*VEC + k];
    float g1 = Arow[i1*VEC + k];
    flat[idx] = __fadd_rn(__fmul_rn(__fsub_rn(1.0f, w), g0), __fmul_rn(w, g1));
  }
  __syncthreads();
  if (t < EMBD) {
    float acc = 0.0f;
    #pragma unroll
    for (int i = 0; i < TT*VEC; i++) acc = __fmaf_rn(flat[i], W1[i*EMBD + t], acc);
    acc = __fadd_rn(acc, b1[t]);
    h[(size_t)n*EMBD + t] = (float)tanh((double)acc);
  }
}

// numpy-mimic BN stats: sequential f32 accumulation over rows (order pinned),
// staged through double-buffered LDS.
#define BCH 128
__global__ __launch_bounds__(256) void k_bnstats(const float* __restrict__ h,
                                                 float* __restrict__ stats)
{
  __shared__ float tile[2][BCH*EMBD];
  __shared__ float smu[32];
  const int t = threadIdx.x;
  const int NCH = NN / BCH;   // 32

  // ---- pass 1: mean ----
  {
    const float4* src = (const float4*)h;
    float4* dst = (float4*)tile[0];
    for (int v = t; v < BCH*8; v += 256) dst[v] = src[v];
  }
  __syncthreads();
  float acc = 0.0f;
  for (int c = 0; c < NCH; c++) {
    if (t >= 64 && c+1 < NCH) {
      const float4* src = (const float4*)(h + (size_t)(c+1)*BCH*EMBD);
      float4* dst = (float4*)tile[(c+1)&1];
      for (int v = t-64; v < BCH*8; v += 192) dst[v] = src[v];
    }
    if (t < 32) {
      const float* p = tile[c&1];
      #pragma unroll 8
      for (int r = 0; r < BCH; r++) acc = __fadd_rn(acc, p[r*EMBD + t]);
    }
    __syncthreads();
  }
  if (t < 32) smu[t] = __fdiv_rn(acc, 4096.0f);
  __syncthreads();

  // ---- pass 2: var ----
  {
    const float4* src = (const float4*)h;
    float4* dst = (float4*)tile[0];
    for (int v = t; v < BCH*8; v += 256) dst[v] = src[v];
  }
  __syncthreads();
  float q = 0.0f;
  for (int c = 0; c < NCH; c++) {
    if (t >= 64 && c+1 < NCH) {
      const float4* src = (const float4*)(h + (size_t)(c+1)*BCH*EMBD);
      float4* dst = (float4*)tile[(c+1)&1];
      for (int v = t-64; v < BCH*8; v += 192) dst[v] = src[v];
    }
    if (t < 32) {
      const float* p = tile[c&1];
      const float m = smu[t];
      #pragma unroll 8
      for (int r = 0; r < BCH; r++) {
        float d = __fsub_rn(p[r*EMBD + t], m);
        q = __fadd_rn(q, __fmul_rn(d, d));
      }
    }
    __syncthreads();
  }
  if (t < 32) {
    float var = __fdiv_rn(q, 4096.0f);
    stats[t] = smu[t];
    stats[32+t] = __fdiv_rn(1.0f, __fsqrt_rn(__fadd_rn(var, 1e-5f)));
  }
}

// emb + per-row sqnorm (numpy pairwise base case, pinned).
// Also initializes rowmin (+inf) / rowmax (0) for k_dtile's int-punned atomics
// (all D values are positive -> int compare == float compare).
__global__ __launch_bounds__(256) void k_emb(
    const float* __restrict__ h, const float* __restrict__ stats,
    const float* __restrict__ gamma, const float* __restrict__ beta,
    float* __restrict__ emb, float* __restrict__ sqn,
    float* __restrict__ rowmin, float* __restrict__ rowmax)
{
  __shared__ float tile[8][32];
  const int t = threadIdx.x;
  const int r = t >> 5;
  const int e = t & 31;
  const int n = blockIdx.x*8 + r;
  float hv = h[(size_t)n*EMBD + e];
  float v = __fadd_rn(__fmul_rn(__fmul_rn(gamma[e], __fsub_rn(hv, stats[e])), stats[32+e]), beta[e]);
  emb[(size_t)n*EMBD + e] = v;
  tile[r][e] = v;
  __syncthreads();
  if (e == 0) {
    float sq[32];
    #pragma unroll
    for (int k = 0; k < 32; k++) { float x = tile[r][k]; sq[k] = __fmul_rn(x, x); }
    float rr[8];
    #pragma unroll
    for (int m = 0; m < 8; m++) rr[m] = sq[m];
    #pragma unroll
    for (int g = 1; g < 4; g++)
      #pragma unroll
      for (int m = 0; m < 8; m++) rr[m] = __fadd_rn(rr[m], sq[8*g + m]);
    float a = __fadd_rn(__fadd_rn(rr[0], rr[1]), __fadd_rn(rr[2], rr[3]));
    float b = __fadd_rn(__fadd_rn(rr[4], rr[5]), __fadd_rn(rr[6], rr[7]));
    sqn[n] = __fadd_rn(a, b);
    rowmin[n] = __int_as_float(0x7f800000);   // +inf
    rowmax[n] = 0.0f;                          // all D > 0
  }
}

// tail of Dpair with pinned f32 rounding (exp in f64 = correctly-rounded f32 exp)
__device__ __forceinline__ float finishD(float dot, float ni, float nj, float denom)
{
  float t1 = __fadd_rn(ni, nj);
  float sq = __fsub_rn(t1, __fmul_rn(2.0f, dot));
  sq = fmaxf(sq, 0.0f);
  float dist = (sq > 0.0f) ? __fsqrt_rn(sq) : 0.0f;
  float q = __fdiv_rn(-dist, denom);
  return (float)exp((double)q);
}

// GEMM-style tiled D stats pass: 64x128 tile, 4x8 register block per thread.
// Computes the numpy pairwise 128-chunk row sums IN REGISTERS via shfl_xor
// (order bit-identical to the old k_drowsum) and per-row min/max via
// int-punned atomics.  Does NOT write D -- k_dstore recomputes it (bit
// identical) with normalization fused, saving the raw-D HBM round-trip.
#define TI 64
#define TJ 128
__global__ __launch_bounds__(256) void k_dtile(
    const float* __restrict__ emb, const float* __restrict__ sqn,
    const float* __restrict__ sigma,
    float* __restrict__ chunks, float* __restrict__ rowmin, float* __restrict__ rowmax)
{
  __shared__ __align__(16) float Ei[TI][36];
  __shared__ __align__(16) float Ej[TJ][36];
  const int t = threadIdx.x;
  const int bi = blockIdx.y;        // i-tile (64 rows)
  const int bj = blockIdx.x;        // j-tile (128 cols) == numpy 128-chunk index
  const int jt = t & 15;
  const int it = t >> 4;

  {
    const float4* si = (const float4*)(emb + (size_t)bi*TI*EMBD);
    for (int v = t; v < TI*8; v += 256) {
      float4 x = si[v];
      *(float4*)&Ei[v >> 3][(v & 7) * 4] = x;
    }
    const float4* sj = (const float4*)(emb + (size_t)bj*TJ*EMBD);
    for (int v = t; v < TJ*8; v += 256) {
      float4 x = sj[v];
      *(float4*)&Ej[v >> 3][(v & 7) * 4] = x;
    }
  }

  const float s0 = sigma[0];
  const float denom = __fmul_rn(2.0f, __fmul_rn(s0, s0));

  float ni[4], nj[8];
  #pragma unroll
  for (int r = 0; r < 4; r++) ni[r] = sqn[bi*TI + it*4 + r];
  #pragma unroll
  for (int u = 0; u < 8; u++) nj[u] = sqn[bj*TJ + jt + 16*u];

  __syncthreads();

  float acc[4][8];
  #pragma unroll
  for (int r = 0; r < 4; r++)
    #pragma unroll
    for (int u = 0; u < 8; u++) acc[r][u] = 0.0f;

  #pragma unroll
  for (int kq = 0; kq < 8; kq++) {
    float4 a[4], b[8];
    #pragma unroll
    for (int r = 0; r < 4; r++) a[r] = *(const float4*)&Ei[it*4 + r][kq*4];
    #pragma unroll
    for (int u = 0; u < 8; u++) b[u] = *(const float4*)&Ej[jt + 16*u][kq*4];
    #pragma unroll
    for (int r = 0; r < 4; r++)
      #pragma unroll
      for (int u = 0; u < 8; u++) {
        float s = acc[r][u];
        s = __fmaf_rn(a[r].x, b[u].x, s);
        s = __fmaf_rn(a[r].y, b[u].y, s);
        s = __fmaf_rn(a[r].z, b[u].z, s);
        s = __fmaf_rn(a[r].w, b[u].w, s);
        acc[r][u] = s;
      }
  }

  const float PINF = __int_as_float(0x7f800000);
  const float NINF = __int_as_float(0xff800000);
  float wv[4][8];
  float thmn[4], thmx[4];
  #pragma unroll
  for (int r = 0; r < 4; r++) {
    const int ig = bi*TI + it*4 + r;
    float mn = PINF, mx = NINF;
    #pragma unroll
    for (int u = 0; u < 8; u++) {
      const int jg = bj*TJ + jt + 16*u;
      float Dv = finishD(acc[r][u], ni[r], nj[u], denom);
      const bool dg = (jg == ig);
      wv[r][u] = dg ? 0.0f : Dv;
      mn = fminf(mn, dg ? PINF : Dv);
      mx = fmaxf(mx, dg ? NINF : Dv);
    }
    thmn[r] = mn; thmx[r] = mx;
  }

  #pragma unroll
  for (int r = 0; r < 4; r++) {
    // ordered numpy base-case rr[m] for m=jt (valid lanes jt<8):
    // own[u] = col m+16u ; partner (jt^8) = col m+8+16u
    float part[8];
    #pragma unroll
    for (int u = 0; u < 8; u++) part[u] = __shfl_xor(wv[r][u], 8, 16);
    float a = wv[r][0];
    a = __fadd_rn(a, part[0]);
    #pragma unroll
    for (int u = 1; u < 8; u++) {
      a = __fadd_rn(a, wv[r][u]);
      a = __fadd_rn(a, part[u]);
    }
    // tree over rr[0..7]: ((r0+r1)+(r2+r3)) + ((r4+r5)+(r6+r7)) at jt==0
    float s1 = __fadd_rn(a,  __shfl_xor(a, 1, 16));
    float s2 = __fadd_rn(s1, __shfl_xor(s1, 2, 16));
    float s3 = __fadd_rn(s2, __shfl_xor(s2, 4, 16));
    // order-free min/max across the 16 jt lanes
    float mn = thmn[r], mx = thmx[r];
    #pragma unroll
    for (int m = 1; m < 16; m <<= 1) {
      mn = fminf(mn, __shfl_xor(mn, m, 16));
      mx = fmaxf(mx, __shfl_xor(mx, m, 16));
    }
    if (jt == 0) {
      const int ig = bi*TI + it*4 + r;
      chunks[(size_t)bj*NN + ig] = s3;
      atomicMin((int*)&rowmin[ig], __float_as_int(mn));
      atomicMax((int*)&rowmax[ig], __float_as_int(mx));
    }
  }
}

// Per-row balanced tree over the 32 chunk sums (identical pairing/order to the
// old k_drowsum cs-tree).  Also zeroes the sim accumulators.
__global__ __launch_bounds__(256) void k_rowcombine(
    const float* __restrict__ chunks, float* __restrict__ rowsum,
    double* __restrict__ sims)
{
  const int i = blockIdx.x*256 + threadIdx.x;
  if (blockIdx.x == 0 && threadIdx.x == 0) { sims[0] = 0.0; sims[1] = 0.0; }
  float ch[32];
  #pragma unroll
  for (int c = 0; c < 32; c++) ch[c] = chunks[(size_t)c*NN + i];
  #pragma unroll
  for (int len = 32; len > 1; len >>= 1)
    #pragma unroll
    for (int k = 0; k < 16; k++)
      if (k < len/2) ch[k] = __fadd_rn(ch[2*k], ch[2*k+1]);
  rowsum[i] = ch[0];
}

// single block: balanced contiguous-pair f32 tree over 4096 row sums, min/max.
__global__ __launch_bounds__(256) void k_dreduce(
    const float* __restrict__ rowsum, const float* __restrict__ rowmin,
    const float* __restrict__ rowmax, float* __restrict__ par)
{
  __shared__ float s[8192];
  __shared__ float rmn[256], rmx[256];
  const int t = threadIdx.x;
  for (int k = t; k < NN; k += 256) s[k] = rowsum[k];
  float mn = __int_as_float(0x7f800000), mx = __int_as_float(0xff800000);
  for (int k = t; k < NN; k += 256) {
    mn = fminf(mn, rowmin[k]);
    mx = fmaxf(mx, rowmax[k]);
  }
  rmn[t] = mn; rmx[t] = mx;
  __syncthreads();
  int src = 0, dst = 4096;
  for (int len = NN; len > 1; len >>= 1) {
    for (int k = t; k < len/2; k += 256)
      s[dst + k] = __fadd_rn(s[src + 2*k], s[src + 2*k+1]);
    __syncthreads();
    src = dst; dst = src + len/2;
  }
  for (int w = 128; w > 0; w >>= 1) {
    if (t < w) {
      rmn[t] = fminf(rmn[t], rmn[t+w]);
      rmx[t] = fmaxf(rmx[t], rmx[t+w]);
    }
    __syncthreads();
  }
  if (t == 0) {
    float S = s[src];
    float avg = __fdiv_rn(S, 16773120.0f);       // n*(n-1)
    float mnr = rmn[0], mxr = rmx[0];
    float mnt = (mnr < avg) ? 0.0f : mnr;
    float mxt = (mxr < avg) ? 0.0f : mxr;
    if (mxt == mnt) mxt = __fadd_rn(mnt, 1.0f);
    par[0] = avg; par[1] = mnt; par[2] = __fsub_rn(mxt, mnt);
  }
}

// Recompute D tiles (bit-identical: same LDS staging, FMA order, finishD) and
// write the FINAL normalized D: o = ((Dv<avg?0:Dv)-mnt)/rng, diag = 1.0.
// Identical ops on identical bits as the old dtile-store + dnorm pair, but
// with 134 MB less HBM traffic.
__global__ __launch_bounds__(256) void k_dstore(
    const float* __restrict__ emb, const float* __restrict__ sqn,
    const float* __restrict__ sigma, const float* __restrict__ par,
    float* __restrict__ Dout)
{
  __shared__ __align__(16) float Ei[TI][36];
  __shared__ __align__(16) float Ej[TJ][36];
  const int t = threadIdx.x;
  const int bi = blockIdx.y;
  const int bj = blockIdx.x;
  const int jt = t & 15;
  const int it = t >> 4;

  {
    const float4* si = (const float4*)(emb + (size_t)bi*TI*EMBD);
    for (int v = t; v < TI*8; v += 256) {
      float4 x = si[v];
      *(float4*)&Ei[v >> 3][(v & 7) * 4] = x;
    }
    const float4* sj = (const float4*)(emb + (size_t)bj*TJ*EMBD);
    for (int v = t; v < TJ*8; v += 256) {
      float4 x = sj[v];
      *(float4*)&Ej[v >> 3][(v & 7) * 4] = x;
    }
  }

  const float s0 = sigma[0];
  const float denom = __fmul_rn(2.0f, __fmul_rn(s0, s0));
  const float avg = par[0], mnt = par[1], rng = par[2];

  float ni[4], nj[8];
  #pragma unroll
  for (int r = 0; r < 4; r++) ni[r] = sqn[bi*TI + it*4 + r];
  #pragma unroll
  for (int u = 0; u < 8; u++) nj[u] = sqn[bj*TJ + jt + 16*u];

  __syncthreads();

  float acc[4][8];
  #pragma unroll
  for (int r = 0; r < 4; r++)
    #pragma unroll
    for (int u = 0; u < 8; u++) acc[r][u] = 0.0f;

  #pragma unroll
  for (int kq = 0; kq < 8; kq++) {
    float4 a[4], b[8];
    #pragma unroll
    for (int r = 0; r < 4; r++) a[r] = *(const float4*)&Ei[it*4 + r][kq*4];
    #pragma unroll
    for (int u = 0; u < 8; u++) b[u] = *(const float4*)&Ej[jt + 16*u][kq*4];
    #pragma unroll
    for (int r = 0; r < 4; r++)
      #pragma unroll
      for (int u = 0; u < 8; u++) {
        float s = acc[r][u];
        s = __fmaf_rn(a[r].x, b[u].x, s);
        s = __fmaf_rn(a[r].y, b[u].y, s);
        s = __fmaf_rn(a[r].z, b[u].z, s);
        s = __fmaf_rn(a[r].w, b[u].w, s);
        acc[r][u] = s;
      }
  }

  #pragma unroll
  for (int r = 0; r < 4; r++) {
    const int ig = bi*TI + it*4 + r;
    float* Dr = Dout + (size_t)ig * NN + bj*TJ;
    #pragma unroll
    for (int u = 0; u < 8; u++) {
      const int jg = bj*TJ + jt + 16*u;
      float Dv = finishD(acc[r][u], ni[r], nj[u], denom);
      float val = (Dv < avg) ? 0.0f : Dv;
      float o = __fdiv_rn(__fsub_rn(val, mnt), rng);
      Dr[jt + 16*u] = (jg == ig) ? 1.0f : o;
    }
  }
}

// Fused L pass (R3 version: dense 12-FMA inner loop, no branching —
// measured 368.9 us / VALUBusy 81.4%; both branchy variants regressed).
__global__ __launch_bounds__(256) void k_lpass(
    const float* __restrict__ L, const int* __restrict__ C,
    const float* __restrict__ PosW, const float* __restrict__ NegW,
    const float* __restrict__ Wp1, const float* __restrict__ bp1,
    const float* __restrict__ Wp2, const float* __restrict__ bp2,
    const float* __restrict__ Wq1, const float* __restrict__ bq1,
    const float* __restrict__ Wq2, const float* __restrict__ bq2,
    const float* __restrict__ Wa, const float* __restrict__ ba,
    float* __restrict__ out_ff, float* __restrict__ posv, float* __restrict__ negv)
{
  __shared__ __align__(16) float buf[SEQ*128];   // 21 KB: L k-half, later apos+aneg
  __shared__ float wps[SEQ], wns[SEQ];
  __shared__ float part[12*64];

  float* apos = buf;
  float* aneg = buf + SEQ*RED;

  const int n = blockIdx.x;
  const int t = threadIdx.x;
  const int w = t >> 6;
  const int lane = t & 63;

  if (t < SEQ) {
    int st = C[2*n], en = C[2*n+1];
    bool pm = (t >= st && t <= en);
    wps[t] = pm ? PosW[(size_t)n*SEQ + t] : 0.0f;
    wns[t] = pm ? 0.0f : NegW[(size_t)n*SEQ + t];
  }

  float accp[11], accq[11], acca[11];
  #pragma unroll
  for (int i = 0; i < 11; i++) { accp[i]=0.f; accq[i]=0.f; acca[i]=0.f; }

  const float4* Lg = (const float4*)(L + (size_t)n * (SEQ*LDIM));

  #pragma unroll
  for (int half = 0; half < 2; half++) {
    {
      float4* B4 = (float4*)buf;
      for (int v = t; v < SEQ*32; v += 256) {
        int s = v >> 5, c = v & 31;
        B4[v] = Lg[s*64 + half*32 + c];
      }
    }
    __syncthreads();
    const float* Wp1h = Wp1 + (size_t)half*128*RED + lane;
    const float* Wq1h = Wq1 + (size_t)half*128*RED + lane;
    const float* Wah  = Wa  + (size_t)half*128*RED + lane;
    for (int k0 = 0; k0 < 128; k0 += 4) {
      float wpr[4], wqr[4], war[4];
      #pragma unroll
      for (int kk = 0; kk < 4; kk++) {
        wpr[kk] = Wp1h[(k0+kk)*RED];
        wqr[kk] = Wq1h[(k0+kk)*RED];
        war[kk] = Wah [(k0+kk)*RED];
      }
      #pragma unroll
      for (int si = 0; si < 11; si++) {
        int s = w + 4*si;
        if (s < SEQ) {
          float4 l4 = *(const float4*)&buf[s*128 + k0];
          accp[si] = __fmaf_rn(l4.x, wpr[0], accp[si]);
          accp[si] = __fmaf_rn(l4.y, wpr[1], accp[si]);
          accp[si] = __fmaf_rn(l4.z, wpr[2], accp[si]);
          accp[si] = __fmaf_rn(l4.w, wpr[3], accp[si]);
          accq[si] = __fmaf_rn(l4.x, wqr[0], accq[si]);
          accq[si] = __fmaf_rn(l4.y, wqr[1], accq[si]);
          accq[si] = __fmaf_rn(l4.z, wqr[2], accq[si]);
          accq[si] = __fmaf_rn(l4.w, wqr[3], accq[si]);
          acca[si] = __fmaf_rn(l4.x, war[0], acca[si]);
          acca[si] = __fmaf_rn(l4.y, war[1], acca[si]);
          acca[si] = __fmaf_rn(l4.z, war[2], acca[si]);
          acca[si] = __fmaf_rn(l4.w, war[3], acca[si]);
        }
      }
    }
    __syncthreads();
  }

  const float bpl = bp1[lane], bql = bq1[lane], bal = ba[lane];
  float ffl = 0.f;
  #pragma unroll
  for (int si = 0; si < 11; si++) {
    int s = w + 4*si;
    if (s < SEQ) {
      float wp = wps[s], wn = wns[s];
      apos[s*RED + lane] = tanhf(__fmaf_rn(wp, accp[si], bpl));
      aneg[s*RED + lane] = tanhf(__fmaf_rn(wn, accq[si], bql));
      ffl += tanhf(__fmaf_rn(wp+wn, acca[si], bal));
    }
  }
  part[(0*4 + w)*64 + lane] = ffl;
  __syncthreads();

  float accP[11], accQ[11];
  #pragma unroll
  for (int i = 0; i < 11; i++) { accP[i]=0.f; accQ[i]=0.f; }
  const float* Wp2l = Wp2 + lane;
  const float* Wq2l = Wq2 + lane;
  for (int k0 = 0; k0 < RED; k0 += 4) {
    float p2[4], q2[4];
    #pragma unroll
    for (int kk = 0; kk < 4; kk++) {
      p2[kk] = Wp2l[(k0+kk)*RED];
      q2[kk] = Wq2l[(k0+kk)*RED];
    }
    #pragma unroll
    for (int si = 0; si < 11; si++) {
      int s = w + 4*si;
      if (s < SEQ) {
        float4 a4 = *(const float4*)&apos[s*RED + k0];
        float4 b4 = *(const float4*)&aneg[s*RED + k0];
        accP[si] = __fmaf_rn(a4.x, p2[0], accP[si]);
        accP[si] = __fmaf_rn(a4.y, p2[1], accP[si]);
        accP[si] = __fmaf_rn(a4.z, p2[2], accP[si]);
        accP[si] = __fmaf_rn(a4.w, p2[3], accP[si]);
        accQ[si] = __fmaf_rn(b4.x, q2[0], accQ[si]);
        accQ[si] = __fmaf_rn(b4.y, q2[1], accQ[si]);
        accQ[si] = __fmaf_rn(b4.z, q2[2], accQ[si]);
        accQ[si] = __fmaf_rn(b4.w, q2[3], accQ[si]);
      }
    }
  }
  const float bp2l = bp2[lane], bq2l = bq2[lane];
  float pl = 0.f, nl = 0.f;
  #pragma unroll
  for (int si = 0; si < 11; si++) {
    int s = w + 4*si;
    if (s < SEQ) {
      pl += tanhf(__fadd_rn(accP[si], bp2l));
      nl += tanhf(__fadd_rn(accQ[si], bq2l));
    }
  }
  part[(1*4 + w)*64 + lane] = pl;
  part[(2*4 + w)*64 + lane] = nl;
  __syncthreads();

  if (w == 0) {
    float s = part[0*256 + 0*64 + lane] + part[0*256 + 1*64 + lane]
            + part[0*256 + 2*64 + lane] + part[0*256 + 3*64 + lane];
    out_ff[(size_t)n*RED + lane] = s * (1.0f/41.0f);
  } else if (w == 1) {
    float s = part[1*256 + 0*64 + lane] + part[1*256 + 1*64 + lane]
            + part[1*256 + 2*64 + lane] + part[1*256 + 3*64 + lane];
    posv[(size_t)n*RED + lane] = s * (1.0f/41.0f);
  } else if (w == 2) {
    float s = part[2*256 + 0*64 + lane] + part[2*256 + 1*64 + lane]
            + part[2*256 + 2*64 + lane] + part[2*256 + 3*64 + lane];
    negv[(size_t)n*RED + lane] = s * (1.0f/41.0f);
  }
}

// 64x64 tile pairwise exp(-dist) sums; z=0: pos-pos, z=1: pos-neg.
// pos-pos is exactly symmetric (commutative fmaf/fadd, same k order), so
// bi>bj blocks are skipped and bi<bj contributions doubled.
__global__ __launch_bounds__(256) void k_sim(
    const float* __restrict__ posv, const float* __restrict__ negv,
    double* __restrict__ sims)
{
  __shared__ float xI[64*64];
  __shared__ float yJ[64*65];
  __shared__ float nxs[64];
  __shared__ double wsum[4];
  const int which = blockIdx.z;
  const int bi = blockIdx.x, bj = blockIdx.y, t = threadIdx.x;
  if (which == 0 && bi > bj) return;
  const float* X = posv;
  const float* Y = which ? negv : posv;
  {
    const float4* X4 = (const float4*)(X + (size_t)(bi*64)*RED);
    float4* xI4 = (float4*)xI;
    for (int v = t; v < 1024; v += 256) xI4[v] = X4[v];
  }
  for (int v = t; v < 4096; v += 256) {
    int r = v >> 6, c = v & 63;
    yJ[r*65+c] = Y[(size_t)(bj*64+r)*RED + c];
  }
  __syncthreads();
  if (t < 64) {
    float s = 0.f;
    #pragma unroll
    for (int k = 0; k < 64; k++) { float v = xI[t*64+k]; s += v*v; }
    nxs[t] = s;
  }
  const int jl = t & 63, iq = t >> 6;
  float yv[64];
  #pragma unroll
  for (int k = 0; k < 64; k++) yv[k] = yJ[jl*65+k];
  float ny = 0.f;
  #pragma unroll
  for (int k = 0; k < 64; k++) ny += yv[k]*yv[k];
  __syncthreads();
  double lsum = 0.0;
  for (int ii = 0; ii < 16; ii++) {
    int il = iq*16 + ii;
    float dot = 0.f;
    #pragma unroll
    for (int k = 0; k < 64; k += 4) {
      float4 x = *(const float4*)&xI[il*64+k];
      dot += x.x*yv[k] + x.y*yv[k+1] + x.z*yv[k+2] + x.w*yv[k+3];
    }
    float sq = fmaxf(nxs[il] + ny - 2.0f*dot, 0.0f);
    float dist = (sq > 0.f) ? sqrtf(sq) : 0.f;
    lsum += (double)expf(-dist);
  }
  #pragma unroll
  for (int m = 32; m >= 1; m >>= 1) lsum += __shfl_down(lsum, m);
  if ((t & 63) == 0) wsum[t>>6] = lsum;
  __syncthreads();
  if (t == 0) {
    double mult = (which == 0 && bi < bj) ? 2.0 : 1.0;
    atomicAdd(&sims[which], mult*(wsum[0]+wsum[1]+wsum[2]+wsum[3]));
  }
}

__global__ void k_loss(const double* __restrict__ sims, float* __restrict__ out_loss) {
  out_loss[0] = (float)(-log(sims[0]/sims[1]));
}

extern "C" void kernel_launch(void* const* d_in, const int* in_sizes, int n_in,
                              void* d_out, int out_size, void* d_ws, size_t ws_size,
                              hipStream_t stream) {
  const float* A     = (const float*)d_in[0];
  const int*   C     = (const int*)  d_in[1];
  const float* L     = (const float*)d_in[2];
  const float* W1    = (const float*)d_in[3];
  const float* b1    = (const float*)d_in[4];
  const float* gamma = (const float*)d_in[5];
  const float* beta  = (const float*)d_in[6];
  const float* sigma = (const float*)d_in[7];
  const float* PosW  = (const float*)d_in[8];
  const float* NegW  = (const float*)d_in[9];
  const float* Wp1   = (const float*)d_in[10];
  const float* bp1   = (const float*)d_in[11];
  const float* Wp2   = (const float*)d_in[12];
  const float* bp2   = (const float*)d_in[13];
  const float* Wq1   = (const float*)d_in[14];
  const float* bq1   = (const float*)d_in[15];
  const float* Wq2   = (const float*)d_in[16];
  const float* bq2   = (const float*)d_in[17];
  const float* Wa    = (const float*)d_in[18];
  const float* ba    = (const float*)d_in[19];

  float* out = (float*)d_out;
  char* ws = (char*)d_ws;
  float* h      = (float*)(ws + WS_H);
  float* chunks = (float*)(ws + WS_CHUNKS);   // aliases h (h dead after k_emb)
  float* emb    = (float*)(ws + WS_EMB);
  float* sqn    = (float*)(ws + WS_SQN);
  float* rowsum = (float*)(ws + WS_ROWSUM);
  float* rowmin = (float*)(ws + WS_ROWMIN);
  float* rowmax = (float*)(ws + WS_ROWMAX);
  float* posv   = (float*)(ws + WS_POSV);
  float* negv   = (float*)(ws + WS_NEGV);
  float* stats  = (float*)(ws + WS_STATS);
  double* sims  = (double*)(ws + WS_SIMS);
  float* par    = (float*)(ws + WS_PAR);

  hipLaunchKernelGGL(k_interp_h, dim3(NN), dim3(64), 0, stream, A, C, W1, b1, h);
  hipLaunchKernelGGL(k_bnstats, dim3(1), dim3(256), 0, stream, h, stats);
  hipLaunchKernelGGL(k_emb, dim3(NN/8), dim3(256), 0, stream, h, stats, gamma, beta, emb, sqn, rowmin, rowmax);
  hipLaunchKernelGGL(k_dtile, dim3(NN/TJ, NN/TI), dim3(256), 0, stream, emb, sqn, sigma, chunks, rowmin, rowmax);
  hipLaunchKernelGGL(k_rowcombine, dim3(16), dim3(256), 0, stream, chunks, rowsum, sims);
  hipLaunchKernelGGL(k_dreduce, dim3(1), dim3(256), 0, stream, rowsum, rowmin, rowmax, par);
  hipLaunchKernelGGL(k_dstore, dim3(NN/TJ, NN/TI), dim3(256), 0, stream, emb, sqn, sigma, par, out + OUT_D);
  hipLaunchKernelGGL(k_lpass, dim3(NN), dim3(256), 0, stream,
                     L, C, PosW, NegW, Wp1, bp1, Wp2, bp2, Wq1, bq1, Wq2, bq2, Wa, ba,
                     out, posv, negv);
  hipLaunchKernelGGL(k_sim, dim3(64,64,2), dim3(256), 0, stream, posv, negv, sims);
  hipLaunchKernelGGL(k_loss, dim3(1), dim3(1), 0, stream, sims, out + OUT_LOSS);
}

// Round 7
// 885.893 us; speedup vs baseline: 1.1059x; 1.1059x over previous
//
#include <hip/hip_runtime.h>
#include <cmath>

#define NN 4096
#define SEQ 41
#define VEC 15
#define TT 8
#define EMBD 32
#define LDIM 256
#define RED 64

// ---- workspace layout (bytes) ----
#define WS_H       0                      // h: N*32 f32  (ALIASED by chunks after k_emb)
#define WS_CHUNKS  0                      // chunks: 32*N f32 (written by k_dtile, after h dead)
#define WS_EMB     524288                 // emb: N*32 f32
#define WS_SQN     1048576                // sqnorm: N f32
#define WS_ROWSUM  1064960                // rowsum: N f32
#define WS_ROWMIN  1081344                // rowmin: N f32
#define WS_ROWMAX  1097728                // rowmax: N f32
#define WS_POSV    1114112                // pos_vec: N*64 f32
#define WS_NEGV    2162688                // neg_vec: N*64 f32
#define WS_STATS   3211264                // mu[32], istd[32] f32
#define WS_SIMS    3211520                // 2 doubles: pos_sim, neg_sim
#define WS_PAR     3211536                // 4 f32: avg, mnt, rng

// output layout: final_feature [N*64], loss [1], D [N*N]
#define OUT_LOSS  (NN*RED)
#define OUT_D     (NN*RED + 1)

// f32 numpy-mimic: interpolation + h = tanh(flat@W1 + b1)
__global__ __launch_bounds__(64) void k_interp_h(
    const float* __restrict__ A, const int* __restrict__ C,
    const float* __restrict__ W1, const float* __restrict__ b1,
    float* __restrict__ h)
{
  __shared__ float flat[TT*VEC];
  const int n = blockIdx.x;
  const int t = threadIdx.x;
  const int st = C[2*n], en = C[2*n+1];
  const int len = en - st + 1;
  const float scale = __fdiv_rn((float)len, 8.0f);   // exact
  const float* Arow = A + ((size_t)n*SEQ + st) * VEC;
  for (int idx = t; idx < TT*VEC; idx += 64) {
    int j = idx / VEC, k = idx - j*VEC;
    float jf = (float)j + 0.5f;                               // exact
    float src = fmaxf(__fsub_rn(__fmul_rn(scale, jf), 0.5f), 0.0f);
    int i0 = min((int)floorf(src), len-1);
    int i1 = min(i0+1, len-1);
    float w = __fsub_rn(src, (float)i0);
    float g0 = Arow[i0*VEC + k];
    float g1 = Arow[i1*VEC + k];
    flat[idx] = __fadd_rn(__fmul_rn(__fsub_rn(1.0f, w), g0), __fmul_rn(w, g1));
  }
  __syncthreads();
  if (t < EMBD) {
    float acc = 0.0f;
    #pragma unroll
    for (int i = 0; i < TT*VEC; i++) acc = __fmaf_rn(flat[i], W1[i*EMBD + t], acc);
    acc = __fadd_rn(acc, b1[t]);
    h[(size_t)n*EMBD + t] = (float)tanh((double)acc);
  }
}

// numpy-mimic BN stats: sequential f32 accumulation over rows (order pinned),
// staged through double-buffered LDS.
#define BCH 128
__global__ __launch_bounds__(256) void k_bnstats(const float* __restrict__ h,
                                                 float* __restrict__ stats)
{
  __shared__ float tile[2][BCH*EMBD];
  __shared__ float smu[32];
  const int t = threadIdx.x;
  const int NCH = NN / BCH;   // 32

  // ---- pass 1: mean ----
  {
    const float4* src = (const float4*)h;
    float4* dst = (float4*)tile[0];
    for (int v = t; v < BCH*8; v += 256) dst[v] = src[v];
  }
  __syncthreads();
  float acc = 0.0f;
  for (int c = 0; c < NCH; c++) {
    if (t >= 64 && c+1 < NCH) {
      const float4* src = (const float4*)(h + (size_t)(c+1)*BCH*EMBD);
      float4* dst = (float4*)tile[(c+1)&1];
      for (int v = t-64; v < BCH*8; v += 192) dst[v] = src[v];
    }
    if (t < 32) {
      const float* p = tile[c&1];
      #pragma unroll 8
      for (int r = 0; r < BCH; r++) acc = __fadd_rn(acc, p[r*EMBD + t]);
    }
    __syncthreads();
  }
  if (t < 32) smu[t] = __fdiv_rn(acc, 4096.0f);
  __syncthreads();

  // ---- pass 2: var ----
  {
    const float4* src = (const float4*)h;
    float4* dst = (float4*)tile[0];
    for (int v = t; v < BCH*8; v += 256) dst[v] = src[v];
  }
  __syncthreads();
  float q = 0.0f;
  for (int c = 0; c < NCH; c++) {
    if (t >= 64 && c+1 < NCH) {
      const float4* src = (const float4*)(h + (size_t)(c+1)*BCH*EMBD);
      float4* dst = (float4*)tile[(c+1)&1];
      for (int v = t-64; v < BCH*8; v += 192) dst[v] = src[v];
    }
    if (t < 32) {
      const float* p = tile[c&1];
      const float m = smu[t];
      #pragma unroll 8
      for (int r = 0; r < BCH; r++) {
        float d = __fsub_rn(p[r*EMBD + t], m);
        q = __fadd_rn(q, __fmul_rn(d, d));
      }
    }
    __syncthreads();
  }
  if (t < 32) {
    float var = __fdiv_rn(q, 4096.0f);
    stats[t] = smu[t];
    stats[32+t] = __fdiv_rn(1.0f, __fsqrt_rn(__fadd_rn(var, 1e-5f)));
  }
}

// emb + per-row sqnorm (numpy pairwise base case, pinned).
// Also initializes rowmin (+inf) / rowmax (0) for k_dtile's int-punned atomics.
__global__ __launch_bounds__(256) void k_emb(
    const float* __restrict__ h, const float* __restrict__ stats,
    const float* __restrict__ gamma, const float* __restrict__ beta,
    float* __restrict__ emb, float* __restrict__ sqn,
    float* __restrict__ rowmin, float* __restrict__ rowmax)
{
  __shared__ float tile[8][32];
  const int t = threadIdx.x;
  const int r = t >> 5;
  const int e = t & 31;
  const int n = blockIdx.x*8 + r;
  float hv = h[(size_t)n*EMBD + e];
  float v = __fadd_rn(__fmul_rn(__fmul_rn(gamma[e], __fsub_rn(hv, stats[e])), stats[32+e]), beta[e]);
  emb[(size_t)n*EMBD + e] = v;
  tile[r][e] = v;
  __syncthreads();
  if (e == 0) {
    float sq[32];
    #pragma unroll
    for (int k = 0; k < 32; k++) { float x = tile[r][k]; sq[k] = __fmul_rn(x, x); }
    float rr[8];
    #pragma unroll
    for (int m = 0; m < 8; m++) rr[m] = sq[m];
    #pragma unroll
    for (int g = 1; g < 4; g++)
      #pragma unroll
      for (int m = 0; m < 8; m++) rr[m] = __fadd_rn(rr[m], sq[8*g + m]);
    float a = __fadd_rn(__fadd_rn(rr[0], rr[1]), __fadd_rn(rr[2], rr[3]));
    float b = __fadd_rn(__fadd_rn(rr[4], rr[5]), __fadd_rn(rr[6], rr[7]));
    sqn[n] = __fadd_rn(a, b);
    rowmin[n] = __int_as_float(0x7f800000);   // +inf
    rowmax[n] = 0.0f;                          // all D > 0
  }
}

// tail of Dpair with pinned f32 rounding (exp in f64 = correctly-rounded f32 exp)
__device__ __forceinline__ float finishD(float dot, float ni, float nj, float denom)
{
  float t1 = __fadd_rn(ni, nj);
  float sq = __fsub_rn(t1, __fmul_rn(2.0f, dot));
  sq = fmaxf(sq, 0.0f);
  float dist = (sq > 0.0f) ? __fsqrt_rn(sq) : 0.0f;
  float q = __fdiv_rn(-dist, denom);
  return (float)exp((double)q);
}

// GEMM-style tiled D: computes D ONCE (the f64-exp is the dominant VALU cost,
// so no recompute pass), writes raw D, and fuses the numpy pairwise 128-chunk
// row sums in registers via shfl_xor + per-row min/max via int-punned atomics.
#define TI 64
#define TJ 128
__global__ __launch_bounds__(256) void k_dtile(
    const float* __restrict__ emb, const float* __restrict__ sqn,
    const float* __restrict__ sigma, float* __restrict__ Dout,
    float* __restrict__ chunks, float* __restrict__ rowmin, float* __restrict__ rowmax)
{
  __shared__ __align__(16) float Ei[TI][36];
  __shared__ __align__(16) float Ej[TJ][36];
  const int t = threadIdx.x;
  const int bi = blockIdx.y;        // i-tile (64 rows)
  const int bj = blockIdx.x;        // j-tile (128 cols) == numpy 128-chunk index
  const int jt = t & 15;
  const int it = t >> 4;

  {
    const float4* si = (const float4*)(emb + (size_t)bi*TI*EMBD);
    for (int v = t; v < TI*8; v += 256) {
      float4 x = si[v];
      *(float4*)&Ei[v >> 3][(v & 7) * 4] = x;
    }
    const float4* sj = (const float4*)(emb + (size_t)bj*TJ*EMBD);
    for (int v = t; v < TJ*8; v += 256) {
      float4 x = sj[v];
      *(float4*)&Ej[v >> 3][(v & 7) * 4] = x;
    }
  }

  const float s0 = sigma[0];
  const float denom = __fmul_rn(2.0f, __fmul_rn(s0, s0));

  float ni[4], nj[8];
  #pragma unroll
  for (int r = 0; r < 4; r++) ni[r] = sqn[bi*TI + it*4 + r];
  #pragma unroll
  for (int u = 0; u < 8; u++) nj[u] = sqn[bj*TJ + jt + 16*u];

  __syncthreads();

  float acc[4][8];
  #pragma unroll
  for (int r = 0; r < 4; r++)
    #pragma unroll
    for (int u = 0; u < 8; u++) acc[r][u] = 0.0f;

  #pragma unroll
  for (int kq = 0; kq < 8; kq++) {
    float4 a[4], b[8];
    #pragma unroll
    for (int r = 0; r < 4; r++) a[r] = *(const float4*)&Ei[it*4 + r][kq*4];
    #pragma unroll
    for (int u = 0; u < 8; u++) b[u] = *(const float4*)&Ej[jt + 16*u][kq*4];
    #pragma unroll
    for (int r = 0; r < 4; r++)
      #pragma unroll
      for (int u = 0; u < 8; u++) {
        float s = acc[r][u];
        s = __fmaf_rn(a[r].x, b[u].x, s);
        s = __fmaf_rn(a[r].y, b[u].y, s);
        s = __fmaf_rn(a[r].z, b[u].z, s);
        s = __fmaf_rn(a[r].w, b[u].w, s);
        acc[r][u] = s;
      }
  }

  const float PINF = __int_as_float(0x7f800000);
  const float NINF = __int_as_float(0xff800000);
  float wv[4][8];
  float thmn[4], thmx[4];
  #pragma unroll
  for (int r = 0; r < 4; r++) {
    const int ig = bi*TI + it*4 + r;
    float* Dr = Dout + (size_t)ig * NN + bj*TJ;
    float mn = PINF, mx = NINF;
    #pragma unroll
    for (int u = 0; u < 8; u++) {
      const int jg = bj*TJ + jt + 16*u;
      float Dv = finishD(acc[r][u], ni[r], nj[u], denom);
      const bool dg = (jg == ig);
      float wq = dg ? 0.0f : Dv;
      wv[r][u] = wq;
      Dr[jt + 16*u] = wq;
      mn = fminf(mn, dg ? PINF : Dv);
      mx = fmaxf(mx, dg ? NINF : Dv);
    }
    thmn[r] = mn; thmx[r] = mx;
  }

  #pragma unroll
  for (int r = 0; r < 4; r++) {
    // ordered numpy base-case rr[m] for m=jt (valid lanes jt<8):
    // own[u] = col m+16u ; partner (jt^8) = col m+8+16u
    float part[8];
    #pragma unroll
    for (int u = 0; u < 8; u++) part[u] = __shfl_xor(wv[r][u], 8, 16);
    float a = wv[r][0];
    a = __fadd_rn(a, part[0]);
    #pragma unroll
    for (int u = 1; u < 8; u++) {
      a = __fadd_rn(a, wv[r][u]);
      a = __fadd_rn(a, part[u]);
    }
    // tree over rr[0..7]: ((r0+r1)+(r2+r3)) + ((r4+r5)+(r6+r7)) at jt==0
    float s1 = __fadd_rn(a,  __shfl_xor(a, 1, 16));
    float s2 = __fadd_rn(s1, __shfl_xor(s1, 2, 16));
    float s3 = __fadd_rn(s2, __shfl_xor(s2, 4, 16));
    // order-free min/max across the 16 jt lanes
    float mn = thmn[r], mx = thmx[r];
    #pragma unroll
    for (int m = 1; m < 16; m <<= 1) {
      mn = fminf(mn, __shfl_xor(mn, m, 16));
      mx = fmaxf(mx, __shfl_xor(mx, m, 16));
    }
    if (jt == 0) {
      const int ig = bi*TI + it*4 + r;
      chunks[(size_t)bj*NN + ig] = s3;
      atomicMin((int*)&rowmin[ig], __float_as_int(mn));
      atomicMax((int*)&rowmax[ig], __float_as_int(mx));
    }
  }
}

// Per-row balanced tree over the 32 chunk sums.  Also zeroes sim accumulators.
__global__ __launch_bounds__(256) void k_rowcombine(
    const float* __restrict__ chunks, float* __restrict__ rowsum,
    double* __restrict__ sims)
{
  const int i = blockIdx.x*256 + threadIdx.x;
  if (blockIdx.x == 0 && threadIdx.x == 0) { sims[0] = 0.0; sims[1] = 0.0; }
  float ch[32];
  #pragma unroll
  for (int c = 0; c < 32; c++) ch[c] = chunks[(size_t)c*NN + i];
  #pragma unroll
  for (int len = 32; len > 1; len >>= 1)
    #pragma unroll
    for (int k = 0; k < 16; k++)
      if (k < len/2) ch[k] = __fadd_rn(ch[2*k], ch[2*k+1]);
  rowsum[i] = ch[0];
}

// single block: balanced contiguous-pair f32 tree over 4096 row sums, min/max.
__global__ __launch_bounds__(256) void k_dreduce(
    const float* __restrict__ rowsum, const float* __restrict__ rowmin,
    const float* __restrict__ rowmax, float* __restrict__ par)
{
  __shared__ float s[8192];
  __shared__ float rmn[256], rmx[256];
  const int t = threadIdx.x;
  for (int k = t; k < NN; k += 256) s[k] = rowsum[k];
  float mn = __int_as_float(0x7f800000), mx = __int_as_float(0xff800000);
  for (int k = t; k < NN; k += 256) {
    mn = fminf(mn, rowmin[k]);
    mx = fmaxf(mx, rowmax[k]);
  }
  rmn[t] = mn; rmx[t] = mx;
  __syncthreads();
  int src = 0, dst = 4096;
  for (int len = NN; len > 1; len >>= 1) {
    for (int k = t; k < len/2; k += 256)
      s[dst + k] = __fadd_rn(s[src + 2*k], s[src + 2*k+1]);
    __syncthreads();
    src = dst; dst = src + len/2;
  }
  for (int w = 128; w > 0; w >>= 1) {
    if (t < w) {
      rmn[t] = fminf(rmn[t], rmn[t+w]);
      rmx[t] = fmaxf(rmx[t], rmx[t+w]);
    }
    __syncthreads();
  }
  if (t == 0) {
    float S = s[src];
    float avg = __fdiv_rn(S, 16773120.0f);       // n*(n-1)
    float mnr = rmn[0], mxr = rmx[0];
    float mnt = (mnr < avg) ? 0.0f : mnr;
    float mxt = (mxr < avg) ? 0.0f : mxr;
    if (mxt == mnt) mxt = __fadd_rn(mnt, 1.0f);
    par[0] = avg; par[1] = mnt; par[2] = __fsub_rn(mxt, mnt);
  }
}

// In-place threshold + normalize of the raw D stored by k_dtile.
__global__ __launch_bounds__(256) void k_dnorm(
    const float* __restrict__ par, float* __restrict__ D)
{
  const int i = blockIdx.x;
  const int t = threadIdx.x;
  const float avg = par[0], mnt = par[1], rng = par[2];
  float4* row = (float4*)(D + (size_t)i*NN);
  const int iv = i >> 2;
  for (int v = t; v < NN/4; v += 256) {
    float4 d = row[v];
    float o[4];
    float in[4] = {d.x, d.y, d.z, d.w};
    #pragma unroll
    for (int u = 0; u < 4; u++) {
      float val = (in[u] < avg) ? 0.0f : in[u];
      o[u] = __fdiv_rn(__fsub_rn(val, mnt), rng);
    }
    if (v == iv) o[i & 3] = 1.0f;
    row[v] = make_float4(o[0], o[1], o[2], o[3]);
  }
}

// Fused L pass, row-exclusive via BRANCHLESS UNIFORM INDIRECTION:
// len <= 8 always, so fixed lists inIdx[8] / outIdx[40] (padded with dummy
// row SEQ=41 whose L-row is zeroed and weights are 0).  Inner loops are
// fully unrolled with compile-time bounds; row indices are loop-invariant
// uniform registers -> no exec-mask divergence (R2 failure) and no scalar
// branches blocking unroll-and-jam (R4 failure).  Layer-1: 92 FMA/quad vs
// 132 dense; layer-2: 56 vs 88.  In/out row dot orders bit-identical; the
// constant-row folds (+33*tcp / +1*tcq) were numerics-validated in R4.
__global__ __launch_bounds__(256) void k_lpass(
    const float* __restrict__ L, const int* __restrict__ C,
    const float* __restrict__ PosW, const float* __restrict__ NegW,
    const float* __restrict__ Wp1, const float* __restrict__ bp1,
    const float* __restrict__ Wp2, const float* __restrict__ bp2,
    const float* __restrict__ Wq1, const float* __restrict__ bq1,
    const float* __restrict__ Wq2, const float* __restrict__ bq2,
    const float* __restrict__ Wa, const float* __restrict__ ba,
    float* __restrict__ out_ff, float* __restrict__ posv, float* __restrict__ negv)
{
  __shared__ __align__(16) float buf[42*128];   // 21 KB: L k-half (+zero row 41), later apos/aneg 42 rows each
  __shared__ float wps[SEQ+1], wns[SEQ+1];
  __shared__ float part[12*64];
  __shared__ __align__(16) float tb1[2*RED];    // tanh(bp1) | tanh(bq1)
  __shared__ int inIdx[8], outIdx[40];

  float* apos = buf;                  // [42][64]
  float* aneg = buf + 42*RED;         // [42][64]

  const int n = blockIdx.x;
  const int t = threadIdx.x;
  const int w = t >> 6;
  const int lane = t & 63;

  const int st = C[2*n], en = C[2*n+1];

  if (t < SEQ) {
    bool pm = (t >= st && t <= en);
    wps[t] = pm ? PosW[(size_t)n*SEQ + t] : 0.0f;
    wns[t] = pm ? 0.0f : NegW[(size_t)n*SEQ + t];
  } else if (t == SEQ) {
    wps[SEQ] = 0.0f; wns[SEQ] = 0.0f;
  }
  if (t < RED) tb1[t] = tanhf(bp1[t]);
  else if (t < 2*RED) tb1[t] = tanhf(bq1[t - RED]);
  if (t == 255) {           // build block-uniform row lists (len in [1,8])
    int ci = 0;
    for (int s = st; s <= en; s++) inIdx[ci++] = s;
    while (ci < 8) inIdx[ci++] = SEQ;
    int co = 0;
    for (int s = 0; s < st; s++) outIdx[co++] = s;
    for (int s = en+1; s < SEQ; s++) outIdx[co++] = s;
    while (co < 40) outIdx[co++] = SEQ;
  }

  float accp[2], accq[10], acca[11];
  #pragma unroll
  for (int i = 0; i < 2; i++) accp[i] = 0.f;
  #pragma unroll
  for (int i = 0; i < 10; i++) accq[i] = 0.f;
  #pragma unroll
  for (int i = 0; i < 11; i++) acca[i] = 0.f;

  const float4* Lg = (const float4*)(L + (size_t)n * (SEQ*LDIM));

  int sIn[2], sOut[10];

  #pragma unroll
  for (int half = 0; half < 2; half++) {
    {
      float4* B4 = (float4*)buf;
      for (int v = t; v < SEQ*32; v += 256) {
        int s = v >> 5, c = v & 31;
        B4[v] = Lg[s*64 + half*32 + c];
      }
      if (t < 32) B4[SEQ*32 + t] = make_float4(0.f, 0.f, 0.f, 0.f);  // zero dummy row
    }
    __syncthreads();
    if (half == 0) {
      sIn[0] = inIdx[w]; sIn[1] = inIdx[w + 4];
      #pragma unroll
      for (int i = 0; i < 10; i++) sOut[i] = outIdx[w + 4*i];
    }
    const float* Wp1h = Wp1 + (size_t)half*128*RED + lane;
    const float* Wq1h = Wq1 + (size_t)half*128*RED + lane;
    const float* Wah  = Wa  + (size_t)half*128*RED + lane;
    for (int k0 = 0; k0 < 128; k0 += 4) {
      float wpr[4], wqr[4], war[4];
      #pragma unroll
      for (int kk = 0; kk < 4; kk++) {
        wpr[kk] = Wp1h[(k0+kk)*RED];
        wqr[kk] = Wq1h[(k0+kk)*RED];
        war[kk] = Wah [(k0+kk)*RED];
      }
      #pragma unroll
      for (int io = 0; io < 2; io++) {
        float4 l4 = *(const float4*)&buf[sIn[io]*128 + k0];
        accp[io] = __fmaf_rn(l4.x, wpr[0], accp[io]);
        accp[io] = __fmaf_rn(l4.y, wpr[1], accp[io]);
        accp[io] = __fmaf_rn(l4.z, wpr[2], accp[io]);
        accp[io] = __fmaf_rn(l4.w, wpr[3], accp[io]);
      }
      #pragma unroll
      for (int oo = 0; oo < 10; oo++) {
        float4 l4 = *(const float4*)&buf[sOut[oo]*128 + k0];
        accq[oo] = __fmaf_rn(l4.x, wqr[0], accq[oo]);
        accq[oo] = __fmaf_rn(l4.y, wqr[1], accq[oo]);
        accq[oo] = __fmaf_rn(l4.z, wqr[2], accq[oo]);
        accq[oo] = __fmaf_rn(l4.w, wqr[3], accq[oo]);
      }
      #pragma unroll
      for (int si = 0; si < 11; si++) {
        int s = w + 4*si;
        if (s < SEQ) {
          float4 l4 = *(const float4*)&buf[s*128 + k0];
          acca[si] = __fmaf_rn(l4.x, war[0], acca[si]);
          acca[si] = __fmaf_rn(l4.y, war[1], acca[si]);
          acca[si] = __fmaf_rn(l4.z, war[2], acca[si]);
          acca[si] = __fmaf_rn(l4.w, war[3], acca[si]);
        }
      }
    }
    __syncthreads();
  }

  const float bpl = bp1[lane], bql = bq1[lane], bal = ba[lane];
  float ffl = 0.f;
  #pragma unroll
  for (int io = 0; io < 2; io++) {
    int s = sIn[io];
    apos[s*RED + lane] = tanhf(__fmaf_rn(wps[s], accp[io], bpl));
  }
  #pragma unroll
  for (int oo = 0; oo < 10; oo++) {
    int s = sOut[oo];
    aneg[s*RED + lane] = tanhf(__fmaf_rn(wns[s], accq[oo], bql));
  }
  #pragma unroll
  for (int si = 0; si < 11; si++) {
    int s = w + 4*si;
    if (s < SEQ) ffl += tanhf(__fmaf_rn(wps[s] + wns[s], acca[si], bal));
  }
  part[(0*4 + w)*64 + lane] = ffl;
  __syncthreads();

  float accP[2], accQ[10];
  float c2p = 0.f, c2q = 0.f;
  #pragma unroll
  for (int i = 0; i < 2; i++) accP[i] = 0.f;
  #pragma unroll
  for (int i = 0; i < 10; i++) accQ[i] = 0.f;
  const float* Wp2l = Wp2 + lane;
  const float* Wq2l = Wq2 + lane;
  for (int k0 = 0; k0 < RED; k0 += 4) {
    float p2[4], q2[4];
    #pragma unroll
    for (int kk = 0; kk < 4; kk++) {
      p2[kk] = Wp2l[(k0+kk)*RED];
      q2[kk] = Wq2l[(k0+kk)*RED];
    }
    float4 tp = *(const float4*)&tb1[k0];
    float4 tq = *(const float4*)&tb1[RED + k0];
    c2p = __fmaf_rn(tp.x, p2[0], c2p);
    c2p = __fmaf_rn(tp.y, p2[1], c2p);
    c2p = __fmaf_rn(tp.z, p2[2], c2p);
    c2p = __fmaf_rn(tp.w, p2[3], c2p);
    c2q = __fmaf_rn(tq.x, q2[0], c2q);
    c2q = __fmaf_rn(tq.y, q2[1], c2q);
    c2q = __fmaf_rn(tq.z, q2[2], c2q);
    c2q = __fmaf_rn(tq.w, q2[3], c2q);
    #pragma unroll
    for (int io = 0; io < 2; io++) {
      float4 a4 = *(const float4*)&apos[sIn[io]*RED + k0];
      accP[io] = __fmaf_rn(a4.x, p2[0], accP[io]);
      accP[io] = __fmaf_rn(a4.y, p2[1], accP[io]);
      accP[io] = __fmaf_rn(a4.z, p2[2], accP[io]);
      accP[io] = __fmaf_rn(a4.w, p2[3], accP[io]);
    }
    #pragma unroll
    for (int oo = 0; oo < 10; oo++) {
      float4 b4 = *(const float4*)&aneg[sOut[oo]*RED + k0];
      accQ[oo] = __fmaf_rn(b4.x, q2[0], accQ[oo]);
      accQ[oo] = __fmaf_rn(b4.y, q2[1], accQ[oo]);
      accQ[oo] = __fmaf_rn(b4.z, q2[2], accQ[oo]);
      accQ[oo] = __fmaf_rn(b4.w, q2[3], accQ[oo]);
    }
  }
  const float bp2l = bp2[lane], bq2l = bq2[lane];
  const float tcp = tanhf(__fadd_rn(c2p, bp2l));
  const float tcq = tanhf(__fadd_rn(c2q, bq2l));
  float pl = 0.f, nl = 0.f;
  #pragma unroll
  for (int io = 0; io < 2; io++) pl += tanhf(__fadd_rn(accP[io], bp2l));
  #pragma unroll
  for (int oo = 0; oo < 10; oo++) nl += tanhf(__fadd_rn(accQ[oo], bq2l));
  part[(1*4 + w)*64 + lane] = pl;
  part[(2*4 + w)*64 + lane] = nl;
  __syncthreads();

  // slot accounting: 8 in-slots give (real in) + (8-nin)*tcp; need nout*tcp
  // total -> +33*tcp (since nout-(8-nin) = 33 always).  40 out-slots give
  // (real out) + (nin-1)*tcq; need nin*tcq -> +1*tcq.
  if (w == 0) {
    float s = part[0*256 + 0*64 + lane] + part[0*256 + 1*64 + lane]
            + part[0*256 + 2*64 + lane] + part[0*256 + 3*64 + lane];
    out_ff[(size_t)n*RED + lane] = s * (1.0f/41.0f);
  } else if (w == 1) {
    float s = part[1*256 + 0*64 + lane] + part[1*256 + 1*64 + lane]
            + part[1*256 + 2*64 + lane] + part[1*256 + 3*64 + lane];
    s += 33.0f * tcp;
    posv[(size_t)n*RED + lane] = s * (1.0f/41.0f);
  } else if (w == 2) {
    float s = part[2*256 + 0*64 + lane] + part[2*256 + 1*64 + lane]
            + part[2*256 + 2*64 + lane] + part[2*256 + 3*64 + lane];
    s += tcq;
    negv[(size_t)n*RED + lane] = s * (1.0f/41.0f);
  }
}

// 64x64 tile pairwise exp(-dist) sums; z=0: pos-pos (symmetric: skip bi>bj,
// double bi<bj), z=1: pos-neg.
__global__ __launch_bounds__(256) void k_sim(
    const float* __restrict__ posv, const float* __restrict__ negv,
    double* __restrict__ sims)
{
  __shared__ float xI[64*64];
  __shared__ float yJ[64*65];
  __shared__ float nxs[64];
  __shared__ double wsum[4];
  const int which = blockIdx.z;
  const int bi = blockIdx.x, bj = blockIdx.y, t = threadIdx.x;
  if (which == 0 && bi > bj) return;
  const float* X = posv;
  const float* Y = which ? negv : posv;
  {
    const float4* X4 = (const float4*)(X + (size_t)(bi*64)*RED);
    float4* xI4 = (float4*)xI;
    for (int v = t; v < 1024; v += 256) xI4[v] = X4[v];
  }
  for (int v = t; v < 4096; v += 256) {
    int r = v >> 6, c = v & 63;
    yJ[r*65+c] = Y[(size_t)(bj*64+r)*RED + c];
  }
  __syncthreads();
  if (t < 64) {
    float s = 0.f;
    #pragma unroll
    for (int k = 0; k < 64; k++) { float v = xI[t*64+k]; s += v*v; }
    nxs[t] = s;
  }
  const int jl = t & 63, iq = t >> 6;
  float yv[64];
  #pragma unroll
  for (int k = 0; k < 64; k++) yv[k] = yJ[jl*65+k];
  float ny = 0.f;
  #pragma unroll
  for (int k = 0; k < 64; k++) ny += yv[k]*yv[k];
  __syncthreads();
  double lsum = 0.0;
  for (int ii = 0; ii < 16; ii++) {
    int il = iq*16 + ii;
    float dot = 0.f;
    #pragma unroll
    for (int k = 0; k < 64; k += 4) {
      float4 x = *(const float4*)&xI[il*64+k];
      dot += x.x*yv[k] + x.y*yv[k+1] + x.z*yv[k+2] + x.w*yv[k+3];
    }
    float sq = fmaxf(nxs[il] + ny - 2.0f*dot, 0.0f);
    float dist = (sq > 0.f) ? sqrtf(sq) : 0.f;
    lsum += (double)expf(-dist);
  }
  #pragma unroll
  for (int m = 32; m >= 1; m >>= 1) lsum += __shfl_down(lsum, m);
  if ((t & 63) == 0) wsum[t>>6] = lsum;
  __syncthreads();
  if (t == 0) {
    double mult = (which == 0 && bi < bj) ? 2.0 : 1.0;
    atomicAdd(&sims[which], mult*(wsum[0]+wsum[1]+wsum[2]+wsum[3]));
  }
}

__global__ void k_loss(const double* __restrict__ sims, float* __restrict__ out_loss) {
  out_loss[0] = (float)(-log(sims[0]/sims[1]));
}

extern "C" void kernel_launch(void* const* d_in, const int* in_sizes, int n_in,
                              void* d_out, int out_size, void* d_ws, size_t ws_size,
                              hipStream_t stream) {
  const float* A     = (const float*)d_in[0];
  const int*   C     = (const int*)  d_in[1];
  const float* L     = (const float*)d_in[2];
  const float* W1    = (const float*)d_in[3];
  const float* b1    = (const float*)d_in[4];
  const float* gamma = (const float*)d_in[5];
  const float* beta  = (const float*)d_in[6];
  const float* sigma = (const float*)d_in[7];
  const float* PosW  = (const float*)d_in[8];
  const float* NegW  = (const float*)d_in[9];
  const float* Wp1   = (const float*)d_in[10];
  const float* bp1   = (const float*)d_in[11];
  const float* Wp2   = (const float*)d_in[12];
  const float* bp2   = (const float*)d_in[13];
  const float* Wq1   = (const float*)d_in[14];
  const float* bq1   = (const float*)d_in[15];
  const float* Wq2   = (const float*)d_in[16];
  const float* bq2   = (const float*)d_in[17];
  const float* Wa    = (const float*)d_in[18];
  const float* ba    = (const float*)d_in[19];

  float* out = (float*)d_out;
  char* ws = (char*)d_ws;
  float* h      = (float*)(ws + WS_H);
  float* chunks = (float*)(ws + WS_CHUNKS);   // aliases h (h dead after k_emb)
  float* emb    = (float*)(ws + WS_EMB);
  float* sqn    = (float*)(ws + WS_SQN);
  float* rowsum = (float*)(ws + WS_ROWSUM);
  float* rowmin = (float*)(ws + WS_ROWMIN);
  float* rowmax = (float*)(ws + WS_ROWMAX);
  float* posv   = (float*)(ws + WS_POSV);
  float* negv   = (float*)(ws + WS_NEGV);
  float* stats  = (float*)(ws + WS_STATS);
  double* sims  = (double*)(ws + WS_SIMS);
  float* par    = (float*)(ws + WS_PAR);

  hipLaunchKernelGGL(k_interp_h, dim3(NN), dim3(64), 0, stream, A, C, W1, b1, h);
  hipLaunchKernelGGL(k_bnstats, dim3(1), dim3(256), 0, stream, h, stats);
  hipLaunchKernelGGL(k_emb, dim3(NN/8), dim3(256), 0, stream, h, stats, gamma, beta, emb, sqn, rowmin, rowmax);
  hipLaunchKernelGGL(k_dtile, dim3(NN/TJ, NN/TI), dim3(256), 0, stream, emb, sqn, sigma, out + OUT_D, chunks, rowmin, rowmax);
  hipLaunchKernelGGL(k_rowcombine, dim3(16), dim3(256), 0, stream, chunks, rowsum, sims);
  hipLaunchKernelGGL(k_dreduce, dim3(1), dim3(256), 0, stream, rowsum, rowmin, rowmax, par);
  hipLaunchKernelGGL(k_dnorm, dim3(NN), dim3(256), 0, stream, par, out + OUT_D);
  hipLaunchKernelGGL(k_lpass, dim3(NN), dim3(256), 0, stream,
                     L, C, PosW, NegW, Wp1, bp1, Wp2, bp2, Wq1, bq1, Wq2, bq2, Wa, ba,
                     out, posv, negv);
  hipLaunchKernelGGL(k_sim, dim3(64,64,2), dim3(256), 0, stream, posv, negv, sims);
  hipLaunchKernelGGL(k_loss, dim3(1), dim3(1), 0, stream, sims, out + OUT_LOSS);
}